// Round 1
// baseline (20232.155 us; speedup 1.0000x reference)
//
#include <hip/hip_runtime.h>
#include <math.h>

typedef __attribute__((ext_vector_type(8))) short s8v;   // 8 bf16 (A/B frag)
typedef __attribute__((ext_vector_type(4))) float f4v;   // 4 fp32 (C/D frag)
typedef unsigned long long u64;

#define TT 512
#define UU 1024
#define HSZ 65536u               // u32 per h slot, frag-packed (see below)

// ---- ws byte offsets ----
#define B_TZ   0ull              // fp32 tz[v][u][g]  16 MB
#define B_A0H  16777216ull       // A0 hi frags  8 MB
#define B_A0L  25165824ull
#define B_A1H  33554432ull       // A1 hi frags 16 MB
#define B_A1L  50331648ull
#define B_H0   67108864ull       // h0 packed u32, 3 slots (768 KB)
#define B_H1   (B_H0 + 3ull*HSZ*4ull)
#define B_BAR  (B_H1 + 3ull*HSZ*4ull)   // barrier block (4 KB)

__device__ __forceinline__ unsigned short f2bf(float x) {
  unsigned u = __float_as_uint(x);
  return (unsigned short)((u + 0x7fffu + ((u >> 16) & 1u)) >> 16);
}

#define MFMA(a, b, c) __builtin_amdgcn_mfma_f32_16x16x32_bf16((a), (b), (c), 0, 0, 0)

__device__ __forceinline__ void stsc(u64* p, u64 v) {
  __hip_atomic_store(p, v, __ATOMIC_RELAXED, __HIP_MEMORY_SCOPE_AGENT);
}

// fast gates: v_exp + v_rcp (err ~1e-7, far below bf16 hi/lo truncation)
__device__ __forceinline__ float sigm(float x) {
  return __builtin_amdgcn_rcpf(1.f + __expf(-x));
}
__device__ __forceinline__ float tanha(float x) {
  return 1.f - 2.f * __builtin_amdgcn_rcpf(1.f + __expf(x + x));
}

// unpack 8 units (2 uint4, each u32 = hi16<<16 | lo16) into hi/lo bf16 frags
__device__ __forceinline__ void unpack8v(uint4 A, uint4 B, s8v& bh, s8v& bl) {
  union { uint4 u; s8v s; } H, L;
  H.u.x = __builtin_amdgcn_perm(A.y, A.x, 0x07060302u);
  H.u.y = __builtin_amdgcn_perm(A.w, A.z, 0x07060302u);
  H.u.z = __builtin_amdgcn_perm(B.y, B.x, 0x07060302u);
  H.u.w = __builtin_amdgcn_perm(B.w, B.z, 0x07060302u);
  L.u.x = __builtin_amdgcn_perm(A.y, A.x, 0x05040100u);
  L.u.y = __builtin_amdgcn_perm(A.w, A.z, 0x05040100u);
  L.u.z = __builtin_amdgcn_perm(B.y, B.x, 0x05040100u);
  L.u.w = __builtin_amdgcn_perm(B.w, B.z, 0x05040100u);
  bh = H.s; bl = L.s;
}

// ---------------- A-fragment pack kernels (unchanged) ----------------
__global__ __launch_bounds__(256) void pack_a0_k(const float* __restrict__ U0,
                                                 unsigned short* __restrict__ A0h,
                                                 unsigned short* __restrict__ A0l) {
  unsigned e = blockIdx.x * 256u + threadIdx.x;          // < 4M
  unsigned j = e & 7u, lane = (e >> 3) & 63u, ch = (e >> 9) & 3u;
  unsigned wv = (e >> 11) & 7u, wg = e >> 14;
  unsigned quad = lane >> 4, col = lane & 15u;
  unsigned k = wv * 128u + ch * 32u + quad * 8u + j;
  unsigned c = (col & 3u) * 1024u + wg * 4u + (col >> 2);
  float x = U0[(size_t)k * 4096u + c];
  unsigned short h = f2bf(x);
  A0h[e] = h;
  A0l[e] = f2bf(x - __uint_as_float(((unsigned)h) << 16));
}

__global__ __launch_bounds__(256) void pack_a1_k(const float* __restrict__ W1,
                                                 const float* __restrict__ U1,
                                                 unsigned short* __restrict__ A1h,
                                                 unsigned short* __restrict__ A1l) {
  unsigned e = blockIdx.x * 256u + threadIdx.x;          // < 8M
  unsigned j = e & 7u, lane = (e >> 3) & 63u, ch = (e >> 9) & 7u;
  unsigned wv = (e >> 12) & 7u, wg = e >> 15;
  unsigned quad = lane >> 4, col = lane & 15u;
  unsigned k = wv * 128u + (ch & 3u) * 32u + quad * 8u + j;
  unsigned c = (col & 3u) * 1024u + wg * 4u + (col >> 2);
  float x = (ch < 4u) ? W1[(size_t)k * 4096u + c] : U1[(size_t)k * 4096u + c];
  unsigned short h = f2bf(x);
  A1h[e] = h;
  A1l[e] = f2bf(x - __uint_as_float(((unsigned)h) << 16));
}

// ---------------- tz = embed @ W0 + b0, stored [v][u][g] (unchanged) ----------------
__global__ __launch_bounds__(256) void tz_gemm_k(const float* __restrict__ embed,
                                                 const float* __restrict__ W0,
                                                 const float* __restrict__ b0,
                                                 float* __restrict__ tz) {
  const int c0 = blockIdx.x << 6;
  const int v0 = blockIdx.y << 6;
  __shared__ float As[32][65];
  __shared__ float Bs[32][65];
  const int tid = threadIdx.x;
  const int tr = tid >> 4, tc = tid & 15;
  float acc[4][4];
#pragma unroll
  for (int r = 0; r < 4; ++r)
#pragma unroll
    for (int c = 0; c < 4; ++c) acc[r][c] = 0.f;

  for (int kc = 0; kc < 512; kc += 32) {
    __syncthreads();
    {
      int kk = tid & 31, vv = tid >> 5;
#pragma unroll
      for (int p = 0; p < 8; ++p)
        As[kk][vv + (p << 3)] = embed[(size_t)(v0 + vv + (p << 3)) * 512 + kc + kk];
    }
    {
      int cc = tid & 63, kk = tid >> 6;
#pragma unroll
      for (int p = 0; p < 8; ++p)
        Bs[kk + (p << 2)][cc] = W0[(size_t)(kc + kk + (p << 2)) * 4096 + c0 + cc];
    }
    __syncthreads();
#pragma unroll 8
    for (int kk = 0; kk < 32; ++kk) {
      float av[4], bv[4];
#pragma unroll
      for (int r = 0; r < 4; ++r) av[r] = As[kk][(tr << 2) + r];
#pragma unroll
      for (int c = 0; c < 4; ++c) bv[c] = Bs[kk][(tc << 2) + c];
#pragma unroll
      for (int r = 0; r < 4; ++r)
#pragma unroll
        for (int c = 0; c < 4; ++c) acc[r][c] = fmaf(av[r], bv[c], acc[r][c]);
    }
  }
#pragma unroll
  for (int r = 0; r < 4; ++r) {
    int v = v0 + (tr << 2) + r;
#pragma unroll
    for (int c = 0; c < 4; ++c) {
      int col = c0 + (tc << 2) + c;
      int g = col >> 10, u = col & 1023;
      tz[(size_t)v * 4096 + (u << 2) + g] = acc[r][c] + b0[col];
    }
  }
}

// ---------------- hierarchical barrier primitives ----------------
__device__ __forceinline__ void arrive(unsigned* xc, unsigned* gc, unsigned* gen, int grp) {
  unsigned old = __hip_atomic_fetch_add(xc + grp * 32, 1u, __ATOMIC_RELAXED,
                                        __HIP_MEMORY_SCOPE_AGENT);
  if ((old & 31u) == 31u) {
    unsigned o2 = __hip_atomic_fetch_add(gc, 1u, __ATOMIC_RELAXED, __HIP_MEMORY_SCOPE_AGENT);
    if ((o2 & 7u) == 7u)
      __hip_atomic_store(gen, (o2 >> 3) + 1u, __ATOMIC_RELAXED, __HIP_MEMORY_SCOPE_AGENT);
  }
}
__device__ __forceinline__ void waitgen(unsigned* gen, unsigned target) {
  while (__hip_atomic_load(gen, __ATOMIC_RELAXED, __HIP_MEMORY_SCOPE_AGENT) < target)
    __builtin_amdgcn_s_sleep(1);
}

// ---------------- persistent MFMA LSTM ----------------
// 256 WGs x 512 thr (1/CU). WG owns 4 units of both layers; weights register-
// stationary (hi+lo bf16).
//
// h broadcast (NEW): frag-packed layout, one u32 (hi16|lo16) per unit:
//   idx_u32(unit,batch) = (wv*4+ch)*2048 + t*512 + half*256 + (quad*16+n)*4 + r
//   where unit = wv*128+ch*32+quad*8+half*4+r, batch = t*16+n.
// Readers issue plain global_load_dwordx4 (fully coalesced: 64 lanes x 16 B
// contiguous = 1 KB/instr) AFTER an acquire-agent fence (buffer_inv) per phase,
// so h is L2-cached and shared by the 32 WGs of each XCD. Producer writes are
// sc0sc1 write-through + vmcnt(0) before arrive, so MALL is the coherence point.
__global__ __launch_bounds__(512) void lstm_coop_k(const int* __restrict__ tokens,
                                                   const float* __restrict__ tz,
                                                   const unsigned short* __restrict__ A0h,
                                                   const unsigned short* __restrict__ A0l,
                                                   const unsigned short* __restrict__ A1h,
                                                   const unsigned short* __restrict__ A1l,
                                                   const float* __restrict__ b1,
                                                   unsigned* __restrict__ h0w,
                                                   unsigned* __restrict__ h1w,
                                                   float* __restrict__ out,
                                                   unsigned* __restrict__ bar) {
  __shared__ float zpf[4 * 2080];           // [gate][unit*520 + wave*64 + batch]
  __shared__ unsigned hx[64 * 5];           // h transpose staging [batch][unit(+pad)]

  const int tid = threadIdx.x;
  const int wg = blockIdx.x;
  const int lane = tid & 63;
  const int wv = __builtin_amdgcn_readfirstlane(tid >> 6);
  const int quad = lane >> 4, n = lane & 15;
  const int j = tid >> 6;                   // unit idx for updater threads (tid<256)
  const int grp = wg & 7;
  const bool bt = (tid == 448);             // barrier thread (wave 7 lane 0)

  unsigned* xcA = bar;        unsigned* xcB = bar + 256;
  unsigned* gcA = bar + 512;  unsigned* gcB = bar + 544;
  unsigned* genA = bar + 576; unsigned* genB = bar + 608;

  // ---- stationary weight fragments ----
  s8v a0h[4], a0l[4], a1h[8], a1l[8];
  {
    const s8v* p0h = (const s8v*)A0h + ((wg * 8 + wv) * 4) * 64 + lane;
    const s8v* p0l = (const s8v*)A0l + ((wg * 8 + wv) * 4) * 64 + lane;
#pragma unroll
    for (int ch = 0; ch < 4; ++ch) { a0h[ch] = p0h[ch * 64]; a0l[ch] = p0l[ch * 64]; }
    const s8v* p1h = (const s8v*)A1h + ((wg * 8 + wv) * 8) * 64 + lane;
    const s8v* p1l = (const s8v*)A1l + ((wg * 8 + wv) * 8) * 64 + lane;
#pragma unroll
    for (int ch = 0; ch < 8; ++ch) { a1h[ch] = p1h[ch * 64]; a1l[ch] = p1l[ch * 64]; }
  }

  float c0 = 0.f, c1 = 0.f, hout = 0.f;
  f4v b1v = {0.f, 0.f, 0.f, 0.f};
  if (tid < 256) {
    b1v.x = b1[0 * 1024 + wg * 4 + j];
    b1v.y = b1[1 * 1024 + wg * 4 + j];
    b1v.z = b1[2 * 1024 + wg * 4 + j];
    b1v.w = b1[3 * 1024 + wg * 4 + j];
  }

  // producer store base (wg bits map 1:1 onto (wv,ch,quad,half))
  const unsigned pcb = ((unsigned)(wg >> 3) << 11) + ((unsigned)(wg & 1) << 8) +
                       ((unsigned)((wg >> 1) & 3) << 6) + ((unsigned)(lane >> 4) << 9) +
                       ((unsigned)(lane & 15) << 2);

  for (int ss = 0; ss <= TT; ++ss) {
    const int s0w = ss % 3, s0r = (ss + 2) % 3;         // h0 slots
    const int s1wr = (ss + 2) % 3, s1r = (ss + 1) % 3;  // h1 slots

    // ---- wait_A: h0(ss-1) stores complete grid-wide ----
    if (bt) waitgen(genA, (unsigned)ss);
    __syncthreads();
    __builtin_amdgcn_fence(__ATOMIC_ACQUIRE, "agent");  // inv L1+L2 -> fresh cached reads

    // ======== h0 pass: acc0 = U0·h0(ss-1), acc1 = W1·h0(ss-1) ========
    f4v tzv = {0.f, 0.f, 0.f, 0.f};
    if (ss < TT && tid < 256) {
      int tok = tokens[lane * TT + ss];
      tzv = ((const f4v*)tz)[(size_t)tok * 1024 + (wg << 2) + j];
    }
    f4v acc0[4], acc1[4];
#pragma unroll
    for (int t = 0; t < 4; ++t) { acc0[t] = (f4v){0,0,0,0}; acc1[t] = (f4v){0,0,0,0}; }
    {
      const uint4* hb4 = (const uint4*)(h0w + s0r * HSZ);
#pragma unroll
      for (int ch = 0; ch < 4; ++ch) {
        const uint4* p = hb4 + (((wv << 2) + ch) << 9) + lane;
        uint4 qa[4], qb[4];
#pragma unroll
        for (int t = 0; t < 4; ++t) { qa[t] = p[t << 7]; qb[t] = p[(t << 7) + 64]; }
#pragma unroll
        for (int t = 0; t < 4; ++t) {
          s8v bh, bl; unpack8v(qa[t], qb[t], bh, bl);
          acc0[t] = MFMA(a0h[ch], bh, acc0[t]);
          acc1[t] = MFMA(a1h[ch], bh, acc1[t]);
          acc0[t] = MFMA(a0l[ch], bh, acc0[t]);
          acc1[t] = MFMA(a1l[ch], bh, acc1[t]);
          acc0[t] = MFMA(a0h[ch], bl, acc0[t]);
          acc1[t] = MFMA(a1h[ch], bl, acc1[t]);
        }
      }
    }

    if (ss < TT) {
#pragma unroll
      for (int t = 0; t < 4; ++t)
#pragma unroll
        for (int r = 0; r < 4; ++r)
          zpf[r * 2080 + quad * 520 + (wv << 6) + t * 16 + n] = acc0[t][r];
      __syncthreads();
      if (tid < 256) {
        f4v s = tzv;
#pragma unroll
        for (int g = 0; g < 4; ++g) {
          float x = 0.f;
#pragma unroll
          for (int w = 0; w < 8; ++w) x += zpf[g * 2080 + j * 520 + (w << 6) + lane];
          s[g] += x;
        }
        float iG = sigm(s.x);
        float fG = sigm(s.y);
        float gG = tanha(s.z);
        float oG = sigm(s.w);
        c0 = fG * c0 + iG * gG;
        float h = oG * tanha(c0);
        unsigned hb16 = (unsigned)f2bf(h);
        unsigned lo16 = (unsigned)f2bf(h - __uint_as_float(hb16 << 16));
        hx[lane * 5 + j] = (hb16 << 16) | lo16;
      }
      __syncthreads();
      if (wv == 7) {
        unsigned v0 = hx[lane * 5 + 0], v1 = hx[lane * 5 + 1];
        unsigned v2 = hx[lane * 5 + 2], v3 = hx[lane * 5 + 3];
        u64* p = (u64*)(h0w + s0w * HSZ + pcb);
        stsc(p, (u64)v0 | ((u64)v1 << 32));
        stsc(p + 1, (u64)v2 | ((u64)v3 << 32));
        asm volatile("s_waitcnt vmcnt(0)" ::: "memory");
        if (lane == 0) arrive(xcA, gcA, genA, grp);
      }
    }

    // ---- wait_B: h1(ss-2) stores complete grid-wide ----
    if (bt && ss >= 1) waitgen(genB, (unsigned)(ss - 1));
    __syncthreads();
    __builtin_amdgcn_fence(__ATOMIC_ACQUIRE, "agent");

    // ======== h1 pass: acc1 += U1·h1(ss-2); layer-1 gates ========
    if (ss >= 1) {
      {
        const uint4* hb4 = (const uint4*)(h1w + s1r * HSZ);
#pragma unroll
        for (int ch = 0; ch < 4; ++ch) {
          const uint4* p = hb4 + (((wv << 2) + ch) << 9) + lane;
          uint4 qa[4], qb[4];
#pragma unroll
          for (int t = 0; t < 4; ++t) { qa[t] = p[t << 7]; qb[t] = p[(t << 7) + 64]; }
#pragma unroll
          for (int t = 0; t < 4; ++t) {
            s8v bh, bl; unpack8v(qa[t], qb[t], bh, bl);
            acc1[t] = MFMA(a1h[4 + ch], bh, acc1[t]);
            acc1[t] = MFMA(a1l[4 + ch], bh, acc1[t]);
            acc1[t] = MFMA(a1h[4 + ch], bl, acc1[t]);
          }
        }
      }
#pragma unroll
      for (int t = 0; t < 4; ++t)
#pragma unroll
        for (int r = 0; r < 4; ++r)
          zpf[r * 2080 + quad * 520 + (wv << 6) + t * 16 + n] = acc1[t][r];
      __syncthreads();
      if (tid < 256) {
        f4v s = b1v;
#pragma unroll
        for (int g = 0; g < 4; ++g) {
          float x = 0.f;
#pragma unroll
          for (int w = 0; w < 8; ++w) x += zpf[g * 2080 + j * 520 + (w << 6) + lane];
          s[g] += x;
        }
        float iG = sigm(s.x);
        float fG = sigm(s.y);
        float gG = tanha(s.z);
        float oG = sigm(s.w);
        c1 = fG * c1 + iG * gG;
        hout = oG * tanha(c1);
        unsigned hb16 = (unsigned)f2bf(hout);
        unsigned lo16 = (unsigned)f2bf(hout - __uint_as_float(hb16 << 16));
        hx[lane * 5 + j] = (hb16 << 16) | lo16;
      }
      __syncthreads();
      if (wv == 7) {
        unsigned v0 = hx[lane * 5 + 0], v1 = hx[lane * 5 + 1];
        unsigned v2 = hx[lane * 5 + 2], v3 = hx[lane * 5 + 3];
        u64* p = (u64*)(h1w + s1wr * HSZ + pcb);
        stsc(p, (u64)v0 | ((u64)v1 << 32));
        stsc(p + 1, (u64)v2 | ((u64)v3 << 32));
        asm volatile("s_waitcnt vmcnt(0)" ::: "memory");
        if (lane == 0) arrive(xcB, gcB, genB, grp);
      }
      // out store: plain/cached, drained by a later waitcnt or kernel end
      if (tid < 256)
        out[(size_t)lane * (TT * UU) + (size_t)(ss - 1) * UU + (wg << 2) + j] = hout;
    }
  }
}

// ---------------- host ----------------
extern "C" void kernel_launch(void* const* d_in, const int* in_sizes, int n_in,
                              void* d_out, int out_size, void* d_ws, size_t ws_size,
                              hipStream_t stream) {
  const int*   tokens = (const int*)d_in[0];
  const float* embed  = (const float*)d_in[1];
  const float* W0     = (const float*)d_in[2];
  const float* U0     = (const float*)d_in[3];
  const float* b0     = (const float*)d_in[4];
  const float* W1     = (const float*)d_in[5];
  const float* U1     = (const float*)d_in[6];
  const float* b1     = (const float*)d_in[7];
  char* ws = (char*)d_ws;
  float*          tz  = (float*)(ws + B_TZ);
  unsigned short* A0h = (unsigned short*)(ws + B_A0H);
  unsigned short* A0l = (unsigned short*)(ws + B_A0L);
  unsigned short* A1h = (unsigned short*)(ws + B_A1H);
  unsigned short* A1l = (unsigned short*)(ws + B_A1L);
  unsigned*       h0w = (unsigned*)(ws + B_H0);
  unsigned*       h1w = (unsigned*)(ws + B_H1);
  unsigned*       bar = (unsigned*)(ws + B_BAR);
  float* out = (float*)d_out;

  // zero h slots + barrier block (ws poisoned 0xAA before every call)
  hipMemsetAsync(ws + B_H0, 0, (size_t)(6ull * HSZ * 4ull + 4096ull), stream);

  pack_a0_k<<<16384, 256, 0, stream>>>(U0, A0h, A0l);
  pack_a1_k<<<32768, 256, 0, stream>>>(W1, U1, A1h, A1l);
  tz_gemm_k<<<dim3(64, 16), 256, 0, stream>>>(embed, W0, b0, tz);

  void* args[] = {(void*)&tokens, (void*)&tz, (void*)&A0h, (void*)&A0l,
                  (void*)&A1h, (void*)&A1l, (void*)&b1, (void*)&h0w, (void*)&h1w,
                  (void*)&out, (void*)&bar};
  hipLaunchCooperativeKernel((void*)lstm_coop_k, dim3(256), dim3(512), args, 0, stream);
}

// Round 2
// 7209.193 us; speedup vs baseline: 2.8064x; 2.8064x over previous
//
#include <hip/hip_runtime.h>
#include <math.h>

typedef __attribute__((ext_vector_type(8))) short s8v;   // 8 bf16 (A/B frag)
typedef __attribute__((ext_vector_type(4))) float f4v;   // 4 fp32 (C/D frag)
typedef unsigned long long u64;

#define TT 512
#define UU 1024
#define HSZ 65536u               // u32 per h slot, frag-packed (see below)

// ---- ws byte offsets ----
#define B_TZ   0ull              // fp32 tz[v][u][g]  16 MB
#define B_A0H  16777216ull       // A0 hi frags  8 MB
#define B_A0L  25165824ull
#define B_A1H  33554432ull       // A1 hi frags 16 MB
#define B_A1L  50331648ull
#define B_H0   67108864ull       // h0 packed u32, 3 slots (768 KB)
#define B_H1   (B_H0 + 3ull*HSZ*4ull)
#define B_BAR  (B_H1 + 3ull*HSZ*4ull)   // barrier block (4 KB)

__device__ __forceinline__ unsigned short f2bf(float x) {
  unsigned u = __float_as_uint(x);
  return (unsigned short)((u + 0x7fffu + ((u >> 16) & 1u)) >> 16);
}

#define MFMA(a, b, c) __builtin_amdgcn_mfma_f32_16x16x32_bf16((a), (b), (c), 0, 0, 0)

__device__ __forceinline__ u64 ldsc(const u64* p) {
  return __hip_atomic_load(p, __ATOMIC_RELAXED, __HIP_MEMORY_SCOPE_AGENT);
}
__device__ __forceinline__ void stsc(u64* p, u64 v) {
  __hip_atomic_store(p, v, __ATOMIC_RELAXED, __HIP_MEMORY_SCOPE_AGENT);
}

// fast gates: v_exp + v_rcp (err ~1e-7, far below bf16 hi/lo truncation)
__device__ __forceinline__ float sigm(float x) {
  return __builtin_amdgcn_rcpf(1.f + __expf(-x));
}
__device__ __forceinline__ float tanha(float x) {
  return 1.f - 2.f * __builtin_amdgcn_rcpf(1.f + __expf(x + x));
}

// unpack 8 units (16 u32 as 4 u64, each u32 = hi16<<16 | lo16) into hi/lo frags
__device__ __forceinline__ void unpack8q(const u64* q, s8v& bh, s8v& bl) {
  union { uint4 u; s8v s; } H, L;
  H.u.x = __builtin_amdgcn_perm((unsigned)(q[0] >> 32), (unsigned)q[0], 0x07060302u);
  H.u.y = __builtin_amdgcn_perm((unsigned)(q[1] >> 32), (unsigned)q[1], 0x07060302u);
  H.u.z = __builtin_amdgcn_perm((unsigned)(q[2] >> 32), (unsigned)q[2], 0x07060302u);
  H.u.w = __builtin_amdgcn_perm((unsigned)(q[3] >> 32), (unsigned)q[3], 0x07060302u);
  L.u.x = __builtin_amdgcn_perm((unsigned)(q[0] >> 32), (unsigned)q[0], 0x05040100u);
  L.u.y = __builtin_amdgcn_perm((unsigned)(q[1] >> 32), (unsigned)q[1], 0x05040100u);
  L.u.z = __builtin_amdgcn_perm((unsigned)(q[2] >> 32), (unsigned)q[2], 0x05040100u);
  L.u.w = __builtin_amdgcn_perm((unsigned)(q[3] >> 32), (unsigned)q[3], 0x05040100u);
  bh = H.s; bl = L.s;
}

// ---------------- A-fragment pack kernels (unchanged) ----------------
__global__ __launch_bounds__(256) void pack_a0_k(const float* __restrict__ U0,
                                                 unsigned short* __restrict__ A0h,
                                                 unsigned short* __restrict__ A0l) {
  unsigned e = blockIdx.x * 256u + threadIdx.x;          // < 4M
  unsigned j = e & 7u, lane = (e >> 3) & 63u, ch = (e >> 9) & 3u;
  unsigned wv = (e >> 11) & 7u, wg = e >> 14;
  unsigned quad = lane >> 4, col = lane & 15u;
  unsigned k = wv * 128u + ch * 32u + quad * 8u + j;
  unsigned c = (col & 3u) * 1024u + wg * 4u + (col >> 2);
  float x = U0[(size_t)k * 4096u + c];
  unsigned short h = f2bf(x);
  A0h[e] = h;
  A0l[e] = f2bf(x - __uint_as_float(((unsigned)h) << 16));
}

__global__ __launch_bounds__(256) void pack_a1_k(const float* __restrict__ W1,
                                                 const float* __restrict__ U1,
                                                 unsigned short* __restrict__ A1h,
                                                 unsigned short* __restrict__ A1l) {
  unsigned e = blockIdx.x * 256u + threadIdx.x;          // < 8M
  unsigned j = e & 7u, lane = (e >> 3) & 63u, ch = (e >> 9) & 7u;
  unsigned wv = (e >> 12) & 7u, wg = e >> 15;
  unsigned quad = lane >> 4, col = lane & 15u;
  unsigned k = wv * 128u + (ch & 3u) * 32u + quad * 8u + j;
  unsigned c = (col & 3u) * 1024u + wg * 4u + (col >> 2);
  float x = (ch < 4u) ? W1[(size_t)k * 4096u + c] : U1[(size_t)k * 4096u + c];
  unsigned short h = f2bf(x);
  A1h[e] = h;
  A1l[e] = f2bf(x - __uint_as_float(((unsigned)h) << 16));
}

// ---------------- tz = embed @ W0 + b0, stored [v][u][g] (unchanged) ----------------
__global__ __launch_bounds__(256) void tz_gemm_k(const float* __restrict__ embed,
                                                 const float* __restrict__ W0,
                                                 const float* __restrict__ b0,
                                                 float* __restrict__ tz) {
  const int c0 = blockIdx.x << 6;
  const int v0 = blockIdx.y << 6;
  __shared__ float As[32][65];
  __shared__ float Bs[32][65];
  const int tid = threadIdx.x;
  const int tr = tid >> 4, tc = tid & 15;
  float acc[4][4];
#pragma unroll
  for (int r = 0; r < 4; ++r)
#pragma unroll
    for (int c = 0; c < 4; ++c) acc[r][c] = 0.f;

  for (int kc = 0; kc < 512; kc += 32) {
    __syncthreads();
    {
      int kk = tid & 31, vv = tid >> 5;
#pragma unroll
      for (int p = 0; p < 8; ++p)
        As[kk][vv + (p << 3)] = embed[(size_t)(v0 + vv + (p << 3)) * 512 + kc + kk];
    }
    {
      int cc = tid & 63, kk = tid >> 6;
#pragma unroll
      for (int p = 0; p < 8; ++p)
        Bs[kk + (p << 2)][cc] = W0[(size_t)(kc + kk + (p << 2)) * 4096 + c0 + cc];
    }
    __syncthreads();
#pragma unroll 8
    for (int kk = 0; kk < 32; ++kk) {
      float av[4], bv[4];
#pragma unroll
      for (int r = 0; r < 4; ++r) av[r] = As[kk][(tr << 2) + r];
#pragma unroll
      for (int c = 0; c < 4; ++c) bv[c] = Bs[kk][(tc << 2) + c];
#pragma unroll
      for (int r = 0; r < 4; ++r)
#pragma unroll
        for (int c = 0; c < 4; ++c) acc[r][c] = fmaf(av[r], bv[c], acc[r][c]);
    }
  }
#pragma unroll
  for (int r = 0; r < 4; ++r) {
    int v = v0 + (tr << 2) + r;
#pragma unroll
    for (int c = 0; c < 4; ++c) {
      int col = c0 + (tc << 2) + c;
      int g = col >> 10, u = col & 1023;
      tz[(size_t)v * 4096 + (u << 2) + g] = acc[r][c] + b0[col];
    }
  }
}

// ---------------- hierarchical barrier primitives ----------------
__device__ __forceinline__ void arrive(unsigned* xc, unsigned* gc, unsigned* gen, int grp) {
  unsigned old = __hip_atomic_fetch_add(xc + grp * 32, 1u, __ATOMIC_RELAXED,
                                        __HIP_MEMORY_SCOPE_AGENT);
  if ((old & 31u) == 31u) {
    unsigned o2 = __hip_atomic_fetch_add(gc, 1u, __ATOMIC_RELAXED, __HIP_MEMORY_SCOPE_AGENT);
    if ((o2 & 7u) == 7u)
      __hip_atomic_store(gen, (o2 >> 3) + 1u, __ATOMIC_RELAXED, __HIP_MEMORY_SCOPE_AGENT);
  }
}
__device__ __forceinline__ void waitgen(unsigned* gen, unsigned target) {
  while (__hip_atomic_load(gen, __ATOMIC_RELAXED, __HIP_MEMORY_SCOPE_AGENT) < target)
    __builtin_amdgcn_s_sleep(1);
}

// ---------------- persistent MFMA LSTM ----------------
// 256 WGs x 512 thr (1/CU). WG owns 4 units of both layers; weights register-
// stationary (hi+lo bf16).
//
// h broadcast: frag-packed layout, one u32 (hi16|lo16) per unit:
//   idx_u32(unit,batch) = (wv*4+ch)*2048 + t*512 + half*256 + lane*4 + r
//   where unit = wv*128+ch*32+quad*8+half*4+r, batch = t*16+n, lane = quad*16+n.
// Readers: MALL-coherent (agent-scope relaxed atomic, sc0sc1) u64 loads — NO
// fences, NO cache invalidates. A wave's load instr covers 512 B contiguous
// = 8 fully-used 64 B MALL lines (vs 32 partially-used lines in the old
// scattered layout: 4x fewer transactions, 4x fewer bytes pulled).
// Producer: sc0sc1 write-through + vmcnt(0) before arrive -> MALL is the
// coherence point.
__global__ __launch_bounds__(512) void lstm_coop_k(const int* __restrict__ tokens,
                                                   const float* __restrict__ tz,
                                                   const unsigned short* __restrict__ A0h,
                                                   const unsigned short* __restrict__ A0l,
                                                   const unsigned short* __restrict__ A1h,
                                                   const unsigned short* __restrict__ A1l,
                                                   const float* __restrict__ b1,
                                                   unsigned* __restrict__ h0w,
                                                   unsigned* __restrict__ h1w,
                                                   float* __restrict__ out,
                                                   unsigned* __restrict__ bar) {
  __shared__ float zpf[4 * 2080];           // [gate][unit*520 + wave*64 + batch]
  __shared__ unsigned hx[64 * 5];           // h transpose staging [batch][unit(+pad)]

  const int tid = threadIdx.x;
  const int wg = blockIdx.x;
  const int lane = tid & 63;
  const int wv = __builtin_amdgcn_readfirstlane(tid >> 6);
  const int quad = lane >> 4, n = lane & 15;
  const int j = tid >> 6;                   // unit idx for updater threads (tid<256)
  const int grp = wg & 7;
  const bool bt = (tid == 448);             // barrier thread (wave 7 lane 0)

  unsigned* xcA = bar;        unsigned* xcB = bar + 256;
  unsigned* gcA = bar + 512;  unsigned* gcB = bar + 544;
  unsigned* genA = bar + 576; unsigned* genB = bar + 608;

  // ---- stationary weight fragments ----
  s8v a0h[4], a0l[4], a1h[8], a1l[8];
  {
    const s8v* p0h = (const s8v*)A0h + ((wg * 8 + wv) * 4) * 64 + lane;
    const s8v* p0l = (const s8v*)A0l + ((wg * 8 + wv) * 4) * 64 + lane;
#pragma unroll
    for (int ch = 0; ch < 4; ++ch) { a0h[ch] = p0h[ch * 64]; a0l[ch] = p0l[ch * 64]; }
    const s8v* p1h = (const s8v*)A1h + ((wg * 8 + wv) * 8) * 64 + lane;
    const s8v* p1l = (const s8v*)A1l + ((wg * 8 + wv) * 8) * 64 + lane;
#pragma unroll
    for (int ch = 0; ch < 8; ++ch) { a1h[ch] = p1h[ch * 64]; a1l[ch] = p1l[ch * 64]; }
  }

  float c0 = 0.f, c1 = 0.f, hout = 0.f;
  f4v b1v = {0.f, 0.f, 0.f, 0.f};
  if (tid < 256) {
    b1v.x = b1[0 * 1024 + wg * 4 + j];
    b1v.y = b1[1 * 1024 + wg * 4 + j];
    b1v.z = b1[2 * 1024 + wg * 4 + j];
    b1v.w = b1[3 * 1024 + wg * 4 + j];
  }

  // producer store base (wg bits map 1:1 onto (wv,ch,quad,half))
  const unsigned pcb = ((unsigned)(wg >> 3) << 11) + ((unsigned)(wg & 1) << 8) +
                       ((unsigned)((wg >> 1) & 3) << 6) + ((unsigned)(lane >> 4) << 9) +
                       ((unsigned)(lane & 15) << 2);

  for (int ss = 0; ss <= TT; ++ss) {
    const int s0w = ss % 3, s0r = (ss + 2) % 3;         // h0 slots
    const int s1wr = (ss + 2) % 3, s1r = (ss + 1) % 3;  // h1 slots

    // ---- wait_A: h0(ss-1) stores complete grid-wide ----
    if (bt) waitgen(genA, (unsigned)ss);
    __syncthreads();

    // ======== h0 pass: acc0 = U0·h0(ss-1), acc1 = W1·h0(ss-1) ========
    f4v tzv = {0.f, 0.f, 0.f, 0.f};
    if (ss < TT && tid < 256) {
      int tok = tokens[lane * TT + ss];
      tzv = ((const f4v*)tz)[(size_t)tok * 1024 + (wg << 2) + j];
    }
    f4v acc0[4], acc1[4];
#pragma unroll
    for (int t = 0; t < 4; ++t) { acc0[t] = (f4v){0,0,0,0}; acc1[t] = (f4v){0,0,0,0}; }
    {
      const u64* hb = (const u64*)(h0w + s0r * HSZ);
#pragma unroll
      for (int ch = 0; ch < 4; ++ch) {
        const u64* p = hb + (((wv << 2) + ch) << 10) + (lane << 1);
        u64 q[4][4];
#pragma unroll
        for (int t = 0; t < 4; ++t) {
          q[t][0] = ldsc(p + (t << 8));
          q[t][1] = ldsc(p + (t << 8) + 1);
          q[t][2] = ldsc(p + (t << 8) + 128);
          q[t][3] = ldsc(p + (t << 8) + 129);
        }
#pragma unroll
        for (int t = 0; t < 4; ++t) {
          s8v bh, bl; unpack8q(q[t], bh, bl);
          acc0[t] = MFMA(a0h[ch], bh, acc0[t]);
          acc1[t] = MFMA(a1h[ch], bh, acc1[t]);
          acc0[t] = MFMA(a0l[ch], bh, acc0[t]);
          acc1[t] = MFMA(a1l[ch], bh, acc1[t]);
          acc0[t] = MFMA(a0h[ch], bl, acc0[t]);
          acc1[t] = MFMA(a1h[ch], bl, acc1[t]);
        }
      }
    }

    if (ss < TT) {
#pragma unroll
      for (int t = 0; t < 4; ++t)
#pragma unroll
        for (int r = 0; r < 4; ++r)
          zpf[r * 2080 + quad * 520 + (wv << 6) + t * 16 + n] = acc0[t][r];
      __syncthreads();
      if (tid < 256) {
        f4v s = tzv;
#pragma unroll
        for (int g = 0; g < 4; ++g) {
          float x = 0.f;
#pragma unroll
          for (int w = 0; w < 8; ++w) x += zpf[g * 2080 + j * 520 + (w << 6) + lane];
          s[g] += x;
        }
        float iG = sigm(s.x);
        float fG = sigm(s.y);
        float gG = tanha(s.z);
        float oG = sigm(s.w);
        c0 = fG * c0 + iG * gG;
        float h = oG * tanha(c0);
        unsigned hb16 = (unsigned)f2bf(h);
        unsigned lo16 = (unsigned)f2bf(h - __uint_as_float(hb16 << 16));
        hx[lane * 5 + j] = (hb16 << 16) | lo16;
      }
      __syncthreads();
      if (wv == 7) {
        unsigned v0 = hx[lane * 5 + 0], v1 = hx[lane * 5 + 1];
        unsigned v2 = hx[lane * 5 + 2], v3 = hx[lane * 5 + 3];
        u64* p = (u64*)(h0w + s0w * HSZ + pcb);
        stsc(p, (u64)v0 | ((u64)v1 << 32));
        stsc(p + 1, (u64)v2 | ((u64)v3 << 32));
        asm volatile("s_waitcnt vmcnt(0)" ::: "memory");
        if (lane == 0) arrive(xcA, gcA, genA, grp);
      }
    }

    // ---- wait_B: h1(ss-2) stores complete grid-wide ----
    if (bt && ss >= 1) waitgen(genB, (unsigned)(ss - 1));
    __syncthreads();

    // ======== h1 pass: acc1 += U1·h1(ss-2); layer-1 gates ========
    if (ss >= 1) {
      {
        const u64* hb = (const u64*)(h1w + s1r * HSZ);
#pragma unroll
        for (int ch = 0; ch < 4; ++ch) {
          const u64* p = hb + (((wv << 2) + ch) << 10) + (lane << 1);
          u64 q[4][4];
#pragma unroll
          for (int t = 0; t < 4; ++t) {
            q[t][0] = ldsc(p + (t << 8));
            q[t][1] = ldsc(p + (t << 8) + 1);
            q[t][2] = ldsc(p + (t << 8) + 128);
            q[t][3] = ldsc(p + (t << 8) + 129);
          }
#pragma unroll
          for (int t = 0; t < 4; ++t) {
            s8v bh, bl; unpack8q(q[t], bh, bl);
            acc1[t] = MFMA(a1h[4 + ch], bh, acc1[t]);
            acc1[t] = MFMA(a1l[4 + ch], bh, acc1[t]);
            acc1[t] = MFMA(a1h[4 + ch], bl, acc1[t]);
          }
        }
      }
#pragma unroll
      for (int t = 0; t < 4; ++t)
#pragma unroll
        for (int r = 0; r < 4; ++r)
          zpf[r * 2080 + quad * 520 + (wv << 6) + t * 16 + n] = acc1[t][r];
      __syncthreads();
      if (tid < 256) {
        f4v s = b1v;
#pragma unroll
        for (int g = 0; g < 4; ++g) {
          float x = 0.f;
#pragma unroll
          for (int w = 0; w < 8; ++w) x += zpf[g * 2080 + j * 520 + (w << 6) + lane];
          s[g] += x;
        }
        float iG = sigm(s.x);
        float fG = sigm(s.y);
        float gG = tanha(s.z);
        float oG = sigm(s.w);
        c1 = fG * c1 + iG * gG;
        hout = oG * tanha(c1);
        unsigned hb16 = (unsigned)f2bf(hout);
        unsigned lo16 = (unsigned)f2bf(hout - __uint_as_float(hb16 << 16));
        hx[lane * 5 + j] = (hb16 << 16) | lo16;
      }
      __syncthreads();
      if (wv == 7) {
        unsigned v0 = hx[lane * 5 + 0], v1 = hx[lane * 5 + 1];
        unsigned v2 = hx[lane * 5 + 2], v3 = hx[lane * 5 + 3];
        u64* p = (u64*)(h1w + s1wr * HSZ + pcb);
        stsc(p, (u64)v0 | ((u64)v1 << 32));
        stsc(p + 1, (u64)v2 | ((u64)v3 << 32));
        asm volatile("s_waitcnt vmcnt(0)" ::: "memory");
        if (lane == 0) arrive(xcB, gcB, genB, grp);
      }
      // out store: plain/cached, drained by a later waitcnt or kernel end
      if (tid < 256)
        out[(size_t)lane * (TT * UU) + (size_t)(ss - 1) * UU + (wg << 2) + j] = hout;
    }
  }
}

// ---------------- host ----------------
extern "C" void kernel_launch(void* const* d_in, const int* in_sizes, int n_in,
                              void* d_out, int out_size, void* d_ws, size_t ws_size,
                              hipStream_t stream) {
  const int*   tokens = (const int*)d_in[0];
  const float* embed  = (const float*)d_in[1];
  const float* W0     = (const float*)d_in[2];
  const float* U0     = (const float*)d_in[3];
  const float* b0     = (const float*)d_in[4];
  const float* W1     = (const float*)d_in[5];
  const float* U1     = (const float*)d_in[6];
  const float* b1     = (const float*)d_in[7];
  char* ws = (char*)d_ws;
  float*          tz  = (float*)(ws + B_TZ);
  unsigned short* A0h = (unsigned short*)(ws + B_A0H);
  unsigned short* A0l = (unsigned short*)(ws + B_A0L);
  unsigned short* A1h = (unsigned short*)(ws + B_A1H);
  unsigned short* A1l = (unsigned short*)(ws + B_A1L);
  unsigned*       h0w = (unsigned*)(ws + B_H0);
  unsigned*       h1w = (unsigned*)(ws + B_H1);
  unsigned*       bar = (unsigned*)(ws + B_BAR);
  float* out = (float*)d_out;

  // zero h slots + barrier block (ws poisoned 0xAA before every call)
  hipMemsetAsync(ws + B_H0, 0, (size_t)(6ull * HSZ * 4ull + 4096ull), stream);

  pack_a0_k<<<16384, 256, 0, stream>>>(U0, A0h, A0l);
  pack_a1_k<<<32768, 256, 0, stream>>>(W1, U1, A1h, A1l);
  tz_gemm_k<<<dim3(64, 16), 256, 0, stream>>>(embed, W0, b0, tz);

  void* args[] = {(void*)&tokens, (void*)&tz, (void*)&A0h, (void*)&A0l,
                  (void*)&A1h, (void*)&A1l, (void*)&b1, (void*)&h0w, (void*)&h1w,
                  (void*)&out, (void*)&bar};
  hipLaunchCooperativeKernel((void*)lstm_coop_k, dim3(256), dim3(512), args, 0, stream);
}